// Round 5
// baseline (107.200 us; speedup 1.0000x reference)
//
#include <hip/hip_runtime.h>
#include <math.h>

// Chamfer loss, B=4, C=3, Np=Ng=8192, fp32 — single dispatch, SINGLE PASS.
// Round 5: 2D register tiling computes each d2 pair ONCE and folds it into
// both directions' mins (halves pair count vs R2-R4's two passes).
// Thread (tx,ty) of a 16x16 block owns RX=8 x-points (registers, whole block)
// and RY=8 y-points per chunk (read from global, L1-resident, 16-lane
// broadcast). Per pair: s = g2 - 2 p.g (3 fma, seed g2 free), x-min on s
// (p2 hoisted), y-side w = s + p2 folded by min3 tree. Per-chunk mny reduced
// across tx via padded LDS (+129 stride -> <=2-way banks), one global
// atomicMin per (block, y). x-mins flushed once per block.
// Cross-block combine: R3/R4 poison-ticket scheme (0xAA ws poison = +inf and
// ticket base); per-batch leaders do the sqrt-sum in parallel.

#define B_       4
#define N_       8192
#define THREADS  256
#define RX       8
#define RY       8
#define XB       128                  // 16 tx * RX
#define XTILES   (N_ / XB)            // 64
#define YSPL     4
#define YRANGE   (N_ / YSPL)          // 2048
#define YC       128                  // 16 ty * RY
#define CHUNKS   (YRANGE / YC)        // 16
#define POISON   0xAAAAAAAAu

// ws (32-bit words):
//   [0, 32768)       x-mins  [b][n]   (uint bit patterns, poison = +inf)
//   [32768, 65536)   y-mins  [b][m]
//   [65536, 65540)   gcnt[b] (per-batch tickets, poison base, 256 blocks each)
//   [65600]          fcnt    (final ticket, 4 leaders)
//   [65664, 65668)   gsum[b] (float batch sums)

__global__ __launch_bounds__(THREADS)
void chamfer_fused_kernel(const float* __restrict__ P, const float* __restrict__ G,
                          unsigned* __restrict__ mins, unsigned* __restrict__ gcnt,
                          unsigned* __restrict__ fcnt, float* __restrict__ gsum,
                          float* __restrict__ out)
{
    __shared__ float lred[16 * 129];   // 8256 B, padded stride 129
    __shared__ unsigned s_ticket;

    const int t     = threadIdx.x;
    const int tx    = t & 15;
    const int ty    = t >> 4;
    const int xtile = blockIdx.x;      // 0..63
    const int yspl  = blockIdx.y;      // 0..3
    const int b     = blockIdx.z;      // 0..3

    const float* Xb = P + (size_t)b * 3 * N_;   // predict -> rows (x)
    const float* Yb = G + (size_t)b * 3 * N_;   // gt      -> cols (y)

    // ---- this thread's RX x-points: -2*coord and p2, registers for life ----
    const int x0 = xtile * XB + tx * RX;
    float4 xa = *(const float4*)&Xb[x0];
    float4 xb4 = *(const float4*)&Xb[x0 + 4];
    float4 ya = *(const float4*)&Xb[N_ + x0];
    float4 yb4 = *(const float4*)&Xb[N_ + x0 + 4];
    float4 za = *(const float4*)&Xb[2 * N_ + x0];
    float4 zb4 = *(const float4*)&Xb[2 * N_ + x0 + 4];
    float px[RX] = {xa.x, xa.y, xa.z, xa.w, xb4.x, xb4.y, xb4.z, xb4.w};
    float py[RX] = {ya.x, ya.y, ya.z, ya.w, yb4.x, yb4.y, yb4.z, yb4.w};
    float pz[RX] = {za.x, za.y, za.z, za.w, zb4.x, zb4.y, zb4.z, zb4.w};

    float m2x[RX], m2y[RX], m2z[RX], p2[RX], mnx[RX];
#pragma unroll
    for (int i = 0; i < RX; ++i) {
        p2[i]  = fmaf(px[i], px[i], fmaf(py[i], py[i], pz[i] * pz[i]));
        m2x[i] = -2.0f * px[i];
        m2y[i] = -2.0f * py[i];
        m2z[i] = -2.0f * pz[i];
        mnx[i] = 3.4e38f;
    }

    const int ybase = yspl * YRANGE;
    const float* ybp = Yb + ybase + ty * RY;
    unsigned* ymin_g = mins + 32768 + (size_t)b * N_ + ybase;

    for (int c = 0; c < CHUNKS; ++c) {
        // this thread's RY y-points for this chunk, straight from global
        const float* yc = ybp + c * YC;
        float4 ga = *(const float4*)&yc[0];
        float4 gb = *(const float4*)&yc[4];
        float4 ha = *(const float4*)&yc[N_];
        float4 hb = *(const float4*)&yc[N_ + 4];
        float4 ka = *(const float4*)&yc[2 * N_];
        float4 kb = *(const float4*)&yc[2 * N_ + 4];
        float gx[RY] = {ga.x, ga.y, ga.z, ga.w, gb.x, gb.y, gb.z, gb.w};
        float gy[RY] = {ha.x, ha.y, ha.z, ha.w, hb.x, hb.y, hb.z, hb.w};
        float gz[RY] = {ka.x, ka.y, ka.z, ka.w, kb.x, kb.y, kb.z, kb.w};

#pragma unroll
        for (int q = 0; q < RY; ++q) {
            float g2 = fmaf(gx[q], gx[q], fmaf(gy[q], gy[q], gz[q] * gz[q]));
            float w[RX];
#pragma unroll
            for (int i = 0; i < RX; ++i) {
                float s = fmaf(m2x[i], gx[q], g2);
                s = fmaf(m2y[i], gy[q], s);
                s = fmaf(m2z[i], gz[q], s);
                mnx[i] = fminf(mnx[i], s);   // x-side (p2 hoisted)
                w[i] = s + p2[i];            // y-side needs full d2
            }
            float t0 = fminf(fminf(w[0], w[1]), w[2]);   // -> v_min3
            float t1 = fminf(fminf(w[3], w[4]), w[5]);
            float t2 = fminf(fminf(w[6], w[7]), t0);
            lred[tx * 129 + ty * RY + q] = fminf(t1, t2);
        }
        __syncthreads();
        if (t < YC) {   // reduce across 16 tx rows, one atomic per y
            float m = lred[t];
#pragma unroll
            for (int k = 1; k < 16; ++k) m = fminf(m, lred[k * 129 + t]);
            atomicMin(&ymin_g[c * YC + t], __float_as_uint(fmaxf(m, 1e-12f)));
        }
        __syncthreads();
    }

    // ---- x-side flush: add p2 back, reduce across 16 ty rows ----
#pragma unroll
    for (int i = 0; i < RX; ++i)
        lred[ty * 129 + tx * RX + i] = mnx[i] + p2[i];
    __syncthreads();
    if (t < XB) {
        float m = lred[t];
#pragma unroll
        for (int k = 1; k < 16; ++k) m = fminf(m, lred[k * 129 + t]);
        atomicMin(&mins[(size_t)b * N_ + xtile * XB + t],
                  __float_as_uint(fmaxf(m, 1e-12f)));
    }
    __syncthreads();

    // ---- per-batch ticket: last of 256 blocks finalizes this batch ----
    if (t == 0) {
        __threadfence();
        s_ticket = atomicAdd(&gcnt[b], 1u);
    }
    __syncthreads();
    if (s_ticket != POISON + (unsigned)(XTILES * YSPL - 1)) return;

    __threadfence();   // acquire: all batch-b atomics visible
    const uint4* vx = (const uint4*)(mins + (size_t)b * N_);
    const uint4* vy = (const uint4*)(mins + 32768 + (size_t)b * N_);
    float acc = 0.0f;
#pragma unroll
    for (int k = 0; k < N_ / 4 / THREADS; ++k) {   // 8
        uint4 a = vx[k * THREADS + t];
        uint4 c4 = vy[k * THREADS + t];
        acc += sqrtf(__uint_as_float(a.x)) + sqrtf(__uint_as_float(a.y))
             + sqrtf(__uint_as_float(a.z)) + sqrtf(__uint_as_float(a.w))
             + sqrtf(__uint_as_float(c4.x)) + sqrtf(__uint_as_float(c4.y))
             + sqrtf(__uint_as_float(c4.z)) + sqrtf(__uint_as_float(c4.w));
    }
    lred[t] = acc;
    __syncthreads();
    for (int off = 128; off > 0; off >>= 1) {
        if (t < off) lred[t] += lred[t + off];
        __syncthreads();
    }
    if (t == 0) {
        gsum[b] = lred[0];
        __threadfence();
        s_ticket = atomicAdd(fcnt, 1u);
    }
    __syncthreads();
    if (s_ticket != POISON + (unsigned)(B_ - 1)) return;

    __threadfence();
    if (t == 0)
        out[0] = (gsum[0] + gsum[1] + gsum[2] + gsum[3]) * (1.0f / 65536.0f);
}

extern "C" void kernel_launch(void* const* d_in, const int* in_sizes, int n_in,
                              void* d_out, int out_size, void* d_ws, size_t ws_size,
                              hipStream_t stream)
{
    const float* P = (const float*)d_in[0];   // predict_pc [4,3,8192]
    const float* G = (const float*)d_in[1];   // gt_pc      [4,3,8192]
    float* out = (float*)d_out;               // scalar

    unsigned* w    = (unsigned*)d_ws;
    unsigned* mins = w;                       // 65536 words
    unsigned* gcnt = w + 65536;               // 4 words
    unsigned* fcnt = w + 65600;               // 1 word
    float*    gsum = (float*)(w + 65664);     // 4 words

    dim3 grid(XTILES, YSPL, B_);              // (64, 4, 4) = 1024 wgs
    chamfer_fused_kernel<<<grid, THREADS, 0, stream>>>(P, G, mins, gcnt, fcnt, gsum, out);
}

// Round 6
// 104.472 us; speedup vs baseline: 1.0261x; 1.0261x over previous
//
#include <hip/hip_runtime.h>
#include <math.h>

// Chamfer loss, B=4, C=3, Np=Ng=8192, fp32 — two-pass, single dispatch.
// Round 6: back to the proven R4 two-pass register-min structure, fixing its
// diagnosed additive LDS+VALU stall:
//  - plain v_fma_f32 (v_pk_fma_f32 measured half-rate on gfx950: R4 busy
//    27.7us == 3 pk@4cyc + min3@2cyc model; packed saves nothing)
//  - RX=16: one broadcast ds_read_b128 serves 16 pairs/lane -> LDS pipe
//    ~10us << VALU ~27us (R4 was 20.5us, additive)
//  - one y-chunk per block (128 y) -> ONE barrier in the whole kernel
//  - manual y+1 prefetch from LDS for read-ahead
//  - grid 1024 blocks x 4 waves = 16 waves/CU for latency hiding
// Cross-block combine: R3/R4 poison-ticket scheme (0xAA ws poison = +inf for
// atomicMin-on-uint-bits and ticket base; no init dispatch).

#define B_       4
#define N_       8192
#define THREADS  256
#define RX       16
#define XB       (THREADS * RX)        // 4096 x-points per block
#define XBLKS    (N_ / XB)             // 2
#define YSPLITS  64
#define YCHUNK   (N_ / YSPLITS)        // 128 y-points per block
#define NGROUPS  8                     // (pass, b)
#define BLKS_PER_GROUP (XBLKS * YSPLITS)   // 128
#define POISON   0xAAAAAAAAu

// ws (32-bit words):
//   [0, 65536)      mins [pass][b][n] (uint bit patterns; poison = +inf)
//   [65536, 65544)  gcnt[8]  (per-(pass,b) tickets, poison base)
//   [65600]         fcnt     (final ticket)
//   [65664, 65672)  gsum[8]  (float group sums)

__global__ __launch_bounds__(THREADS, 4)
void chamfer_fused_kernel(const float* __restrict__ P, const float* __restrict__ G,
                          unsigned* __restrict__ mins, unsigned* __restrict__ gcnt,
                          unsigned* __restrict__ fcnt, float* __restrict__ gsum,
                          float* __restrict__ out)
{
    __shared__ float4 ytile[YCHUNK + 4];   // +pad so the j+1 prefetch never branches
    __shared__ float red[THREADS];
    __shared__ unsigned s_ticket;

    const int t      = threadIdx.x;
    const int xblk   = blockIdx.x;     // 0..1
    const int ysplit = blockIdx.y;     // 0..63
    const int bz     = blockIdx.z;     // 0..7
    const int pass   = bz >> 2;        // 0: X=predict, 1: X=gt
    const int b      = bz & 3;
    const int grp    = bz;             // == pass*4 + b

    const float* Xb = (pass ? G : P) + (size_t)b * 3 * N_;
    const float* Yb = (pass ? P : G) + (size_t)b * 3 * N_;

    // ---- stage this block's single 128-y chunk: (gx, gy, gz, |g|^2) ----
    if (t < YCHUNK) {
        const int n = ysplit * YCHUNK + t;
        float gx = Yb[n];
        float gy = Yb[N_ + n];
        float gz = Yb[2 * N_ + n];
        ytile[t] = make_float4(gx, gy, gz, fmaf(gx, gx, fmaf(gy, gy, gz * gz)));
    }

    // ---- RX x-points per thread, registers for the whole kernel ----
    const int xbase = xblk * XB;
    float m2x[RX], m2y[RX], m2z[RX], p2[RX], mn[RX];
#pragma unroll
    for (int i = 0; i < RX; ++i) {
        const int n = xbase + i * THREADS + t;   // stride-256: coalesced
        float px = Xb[n];
        float py = Xb[N_ + n];
        float pz = Xb[2 * N_ + n];
        p2[i]  = fmaf(px, px, fmaf(py, py, pz * pz));
        m2x[i] = -2.0f * px;
        m2y[i] = -2.0f * py;
        m2z[i] = -2.0f * pz;
        mn[i]  = 3.4e38f;
    }
    __syncthreads();   // the only barrier before the epilogue

    // ---- sweep 128 y: per y one broadcast b128 + 16 independent 4-op chains
    float4 g = ytile[0];
#pragma unroll 2
    for (int j = 0; j < YCHUNK; ++j) {
        float4 gn = ytile[j + 1];      // prefetch (pad makes j=127 safe)
#pragma unroll
        for (int i = 0; i < RX; ++i) {
            float s = fmaf(m2x[i], g.x, g.w);   // seed = |g|^2 (free src2)
            s = fmaf(m2y[i], g.y, s);
            s = fmaf(m2z[i], g.z, s);
            mn[i] = fminf(mn[i], s);            // p2 shift-invariant, added later
        }
        g = gn;
    }

    // ---- flush: d2 = mn + p2, clamp, atomicMin on uint bits ----
    unsigned* mybase = mins + (size_t)grp * N_ + xbase;
#pragma unroll
    for (int i = 0; i < RX; ++i) {
        float v = fmaxf(mn[i] + p2[i], 1e-12f);
        atomicMin(&mybase[i * THREADS + t], __float_as_uint(v));
    }

    // ---- per-(pass,b) ticket: last of 128 blocks finalizes the group ----
    __syncthreads();               // drains vmcnt: this block's atomics done
    if (t == 0) {
        __threadfence();           // release
        s_ticket = atomicAdd(&gcnt[grp], 1u);
    }
    __syncthreads();
    if (s_ticket != POISON + (unsigned)(BLKS_PER_GROUP - 1)) return;

    // ---- group leader: 8192 mins final -> sqrt-sum ----
    __threadfence();               // acquire
    const uint4* v = (const uint4*)(mins + (size_t)grp * N_);
    float acc = 0.0f;
#pragma unroll
    for (int k = 0; k < N_ / 4 / THREADS; ++k) {   // 8
        uint4 q = v[k * THREADS + t];
        acc += sqrtf(__uint_as_float(q.x)) + sqrtf(__uint_as_float(q.y))
             + sqrtf(__uint_as_float(q.z)) + sqrtf(__uint_as_float(q.w));
    }
    red[t] = acc;
    __syncthreads();
    for (int off = 128; off > 0; off >>= 1) {
        if (t < off) red[t] += red[t + off];
        __syncthreads();
    }
    if (t == 0) {
        gsum[grp] = red[0];
        __threadfence();           // release
        s_ticket = atomicAdd(fcnt, 1u);
    }
    __syncthreads();
    if (s_ticket != POISON + (unsigned)(NGROUPS - 1)) return;

    // ---- final leader: sum 8 group sums, write scalar ----
    __threadfence();               // acquire
    if (t == 0) {
        float s = 0.0f;
#pragma unroll
        for (int k = 0; k < NGROUPS; ++k) s += gsum[k];
        out[0] = s * (1.0f / 65536.0f);   // denom = B*(Ng+Np), both directions
    }
}

extern "C" void kernel_launch(void* const* d_in, const int* in_sizes, int n_in,
                              void* d_out, int out_size, void* d_ws, size_t ws_size,
                              hipStream_t stream)
{
    const float* P = (const float*)d_in[0];   // predict_pc [4,3,8192]
    const float* G = (const float*)d_in[1];   // gt_pc      [4,3,8192]
    float* out = (float*)d_out;               // scalar

    unsigned* w    = (unsigned*)d_ws;
    unsigned* mins = w;                       // 65536 words
    unsigned* gcnt = w + 65536;               // 8 words
    unsigned* fcnt = w + 65600;               // 1 word
    float*    gsum = (float*)(w + 65664);     // 8 words

    dim3 grid(XBLKS, YSPLITS, 2 * B_);        // (2, 64, 8) = 1024 blocks
    chamfer_fused_kernel<<<grid, THREADS, 0, stream>>>(P, G, mins, gcnt, fcnt, gsum, out);
}

// Round 7
// 104.015 us; speedup vs baseline: 1.0306x; 1.0044x over previous
//
#include <hip/hip_runtime.h>
#include <math.h>

// Chamfer loss, B=4, C=3, Np=Ng=8192, fp32 — two-pass, single dispatch.
// Round 7: R4's packed math in R6's overlap-friendly structure.
//  - R6 proved scalar v_fma issues at ~2.9 cyc (m07's 103/157 TF) -> scalar
//    path is roofed at 48.7us busy. v_pk_fma_f32 (4 cyc, 2 results) +
//    v_min3_f32 = 15 cyc / 2 pairs = 7.5 cyc/pair -> 25.6us busy floor.
//  - x-constants packed 2-per-VGPR-pair; the needed half is broadcast to
//    both lanes of the pk op via VOP3P op_sel/op_sel_hi (no duplication,
//    80 persistent VGPRs like R6).
//  - structure unchanged from R6: RX=16, one y-chunk (64 y-pairs) per block,
//    ONE barrier, rolling ds_read_b128 prefetch, 1024 blocks, poison-ticket
//    combine (0xAA ws poison = +inf for uint-min and ticket base).

#define B_       4
#define N_       8192
#define THREADS  256
#define RX       16
#define XB       (THREADS * RX)        // 4096 x-points per block
#define XBLKS    (N_ / XB)             // 2
#define YSPLITS  64
#define YCHUNK   (N_ / YSPLITS)        // 128 y-points per block (64 pairs)
#define NGROUPS  8                     // (pass, b)
#define BLKS_PER_GROUP (XBLKS * YSPLITS)   // 128
#define POISON   0xAAAAAAAAu

typedef float v2f __attribute__((ext_vector_type(2)));

// lo-half of src0 broadcast to both result halves
__device__ __forceinline__ v2f pk_fma_blo(v2f a, v2f b, v2f c) {
    v2f d;
    asm("v_pk_fma_f32 %0, %1, %2, %3 op_sel:[0,0,0] op_sel_hi:[0,1,1]"
        : "=v"(d) : "v"(a), "v"(b), "v"(c));
    return d;
}
// hi-half of src0 broadcast to both result halves
__device__ __forceinline__ v2f pk_fma_bhi(v2f a, v2f b, v2f c) {
    v2f d;
    asm("v_pk_fma_f32 %0, %1, %2, %3 op_sel:[1,0,0] op_sel_hi:[1,1,1]"
        : "=v"(d) : "v"(a), "v"(b), "v"(c));
    return d;
}

// ws (32-bit words):
//   [0, 65536)      mins [pass][b][n] (uint bit patterns; poison = +inf)
//   [65536, 65544)  gcnt[8]  (per-(pass,b) tickets, poison base)
//   [65600]         fcnt     (final ticket)
//   [65664, 65672)  gsum[8]  (float group sums)

__global__ __launch_bounds__(THREADS, 4)
void chamfer_fused_kernel(const float* __restrict__ P, const float* __restrict__ G,
                          unsigned* __restrict__ mins, unsigned* __restrict__ gcnt,
                          unsigned* __restrict__ fcnt, float* __restrict__ gsum,
                          float* __restrict__ out)
{
    __shared__ float4 ytile[2 * (YCHUNK / 2) + 4];   // pair-interleaved, +pad
    __shared__ float red[THREADS];
    __shared__ unsigned s_ticket;

    const int t      = threadIdx.x;
    const int xblk   = blockIdx.x;     // 0..1
    const int ysplit = blockIdx.y;     // 0..63
    const int bz     = blockIdx.z;     // 0..7
    const int pass   = bz >> 2;        // 0: X=predict, 1: X=gt
    const int b      = bz & 3;
    const int grp    = bz;

    const float* Xb = (pass ? G : P) + (size_t)b * 3 * N_;
    const float* Yb = (pass ? P : G) + (size_t)b * 3 * N_;

    // ---- stage 64 y-pairs: slot 2jj = (gx0,gx1,gy0,gy1), 2jj+1 = (gz0,gz1,g20,g21)
    if (t < YCHUNK / 2) {
        const int n0 = ysplit * YCHUNK + 2 * t;
        float2 x01 = *(const float2*)&Yb[n0];
        float2 y01 = *(const float2*)&Yb[N_ + n0];
        float2 z01 = *(const float2*)&Yb[2 * N_ + n0];
        float w0 = fmaf(x01.x, x01.x, fmaf(y01.x, y01.x, z01.x * z01.x));
        float w1 = fmaf(x01.y, x01.y, fmaf(y01.y, y01.y, z01.y * z01.y));
        ytile[2 * t]     = make_float4(x01.x, x01.y, y01.x, y01.y);
        ytile[2 * t + 1] = make_float4(z01.x, z01.y, w0, w1);
    }

    // ---- RX x-points per thread; -2*coord packed 2-per-pair ----
    const int xbase = xblk * XB;
    v2f cm2x[RX / 2], cm2y[RX / 2], cm2z[RX / 2];
    float p2[RX], mn[RX];
#pragma unroll
    for (int k = 0; k < RX / 2; ++k) {
        const int n0 = xbase + (2 * k) * THREADS + t;       // even x-point
        const int n1 = xbase + (2 * k + 1) * THREADS + t;   // odd x-point
        float px0 = Xb[n0], py0 = Xb[N_ + n0], pz0 = Xb[2 * N_ + n0];
        float px1 = Xb[n1], py1 = Xb[N_ + n1], pz1 = Xb[2 * N_ + n1];
        p2[2 * k]     = fmaf(px0, px0, fmaf(py0, py0, pz0 * pz0));
        p2[2 * k + 1] = fmaf(px1, px1, fmaf(py1, py1, pz1 * pz1));
        cm2x[k] = (v2f){-2.0f * px0, -2.0f * px1};
        cm2y[k] = (v2f){-2.0f * py0, -2.0f * py1};
        cm2z[k] = (v2f){-2.0f * pz0, -2.0f * pz1};
        mn[2 * k] = 3.4e38f;
        mn[2 * k + 1] = 3.4e38f;
    }
    __syncthreads();   // the only barrier before the epilogue

    // ---- sweep 64 y-pairs: per pair 2 b128 + 16 x (3 pk_fma + 1 min3) ----
    float4 a4 = ytile[0];
    float4 b4 = ytile[1];
    for (int jj = 0; jj < YCHUNK / 2; ++jj) {
        float4 a4n = ytile[2 * jj + 2];   // rolling prefetch (pad-safe)
        float4 b4n = ytile[2 * jj + 3];
        v2f gx2 = (v2f){a4.x, a4.y};
        v2f gy2 = (v2f){a4.z, a4.w};
        v2f gz2 = (v2f){b4.x, b4.y};
        v2f gw2 = (v2f){b4.z, b4.w};
#pragma unroll
        for (int k = 0; k < RX / 2; ++k) {
            v2f s = pk_fma_blo(cm2z[k], gz2, gw2);   // seed = |g|^2 pair
            s = pk_fma_blo(cm2y[k], gy2, s);
            s = pk_fma_blo(cm2x[k], gx2, s);
            mn[2 * k] = fminf(fminf(mn[2 * k], s.x), s.y);     // v_min3
            v2f u = pk_fma_bhi(cm2z[k], gz2, gw2);
            u = pk_fma_bhi(cm2y[k], gy2, u);
            u = pk_fma_bhi(cm2x[k], gx2, u);
            mn[2 * k + 1] = fminf(fminf(mn[2 * k + 1], u.x), u.y);
        }
        a4 = a4n;
        b4 = b4n;
    }

    // ---- flush: d2 = mn + p2, clamp, atomicMin on uint bits ----
    unsigned* mybase = mins + (size_t)grp * N_ + xbase;
#pragma unroll
    for (int i = 0; i < RX; ++i) {
        float v = fmaxf(mn[i] + p2[i], 1e-12f);
        atomicMin(&mybase[i * THREADS + t], __float_as_uint(v));
    }

    // ---- per-(pass,b) ticket: last of 128 blocks finalizes the group ----
    __syncthreads();               // drains vmcnt: this block's atomics done
    if (t == 0) {
        __threadfence();           // release
        s_ticket = atomicAdd(&gcnt[grp], 1u);
    }
    __syncthreads();
    if (s_ticket != POISON + (unsigned)(BLKS_PER_GROUP - 1)) return;

    // ---- group leader: 8192 mins final -> sqrt-sum ----
    __threadfence();               // acquire
    const uint4* v = (const uint4*)(mins + (size_t)grp * N_);
    float acc = 0.0f;
#pragma unroll
    for (int k = 0; k < N_ / 4 / THREADS; ++k) {   // 8
        uint4 q = v[k * THREADS + t];
        acc += sqrtf(__uint_as_float(q.x)) + sqrtf(__uint_as_float(q.y))
             + sqrtf(__uint_as_float(q.z)) + sqrtf(__uint_as_float(q.w));
    }
    red[t] = acc;
    __syncthreads();
    for (int off = 128; off > 0; off >>= 1) {
        if (t < off) red[t] += red[t + off];
        __syncthreads();
    }
    if (t == 0) {
        gsum[grp] = red[0];
        __threadfence();           // release
        s_ticket = atomicAdd(fcnt, 1u);
    }
    __syncthreads();
    if (s_ticket != POISON + (unsigned)(NGROUPS - 1)) return;

    // ---- final leader: sum 8 group sums, write scalar ----
    __threadfence();               // acquire
    if (t == 0) {
        float s = 0.0f;
#pragma unroll
        for (int k = 0; k < NGROUPS; ++k) s += gsum[k];
        out[0] = s * (1.0f / 65536.0f);   // denom = B*(Ng+Np), both directions
    }
}

extern "C" void kernel_launch(void* const* d_in, const int* in_sizes, int n_in,
                              void* d_out, int out_size, void* d_ws, size_t ws_size,
                              hipStream_t stream)
{
    const float* P = (const float*)d_in[0];   // predict_pc [4,3,8192]
    const float* G = (const float*)d_in[1];   // gt_pc      [4,3,8192]
    float* out = (float*)d_out;               // scalar

    unsigned* w    = (unsigned*)d_ws;
    unsigned* mins = w;                       // 65536 words
    unsigned* gcnt = w + 65536;               // 8 words
    unsigned* fcnt = w + 65600;               // 1 word
    float*    gsum = (float*)(w + 65664);     // 8 words

    dim3 grid(XBLKS, YSPLITS, 2 * B_);        // (2, 64, 8) = 1024 blocks
    chamfer_fused_kernel<<<grid, THREADS, 0, stream>>>(P, G, mins, gcnt, fcnt, gsum, out);
}